// Round 5
// baseline (960.789 us; speedup 1.0000x reference)
//
#include <hip/hip_runtime.h>

#define B_TOT 65536
#define SEQ   32

typedef __bf16 bf16_8 __attribute__((ext_vector_type(8)));
typedef __bf16 bf16_4 __attribute__((ext_vector_type(4)));
typedef float  float4v __attribute__((ext_vector_type(4)));
typedef float  float2v __attribute__((ext_vector_type(2)));

#define SC1 (-1.4426950408889634f)   // -log2(e): i,f,o gate rows
#define SC2 (-2.8853900817779268f)   // -2*log2(e): g gate rows (and tanh(c2))

__device__ inline unsigned short f2bf(float f){
    unsigned u = __builtin_bit_cast(unsigned, f);
    u += 0x7FFFu + ((u >> 16) & 1u);           // round-to-nearest-even
    return (unsigned short)(u >> 16);
}

// ---- prep: W_eff = w_hh.T + w_pos.T @ (w_emb.T @ w_ih.T); biases folded;
// rows pre-scaled by -log2e (i,f,o) / -2log2e (g) so exp2 needs no mul. ----
__global__ void prep_kernel(const float* __restrict__ w_ih,
                            const float* __restrict__ w_hh,
                            const float* __restrict__ b_ih,
                            const float* __restrict__ b_hh,
                            const float* __restrict__ w_emb,
                            const float* __restrict__ b_emb,
                            const float* __restrict__ w_pos,
                            const float* __restrict__ b_pos,
                            unsigned short* __restrict__ weff,
                            float* __restrict__ beff,
                            float* __restrict__ m2,
                            unsigned short* __restrict__ wposA)
{
    int n = threadIdx.x;                       // 512 threads, one gate row each
    float m20 = 0.f, m21 = 0.f, bi = 0.f;
    for (int e = 0; e < 64; ++e){
        float wv = w_ih[n*64 + e];
        m20 += w_emb[e*2 + 0] * wv;
        m21 += w_emb[e*2 + 1] * wv;
        bi  += b_emb[e] * wv;
    }
    float sc = ((n >> 7) == 2) ? SC2 : SC1;    // gate order [i,f,g,o]
    m2[n]       = m20 * sc;
    m2[512 + n] = m21 * sc;
    beff[n] = (b_ih[n] + b_hh[n] + bi + b_pos[0]*m20 + b_pos[1]*m21) * sc;
    for (int k = 0; k < 128; ++k){
        float wv = w_hh[n*128 + k] + w_pos[k]*m20 + w_pos[128 + k]*m21;
        weff[n*128 + k] = f2bf(wv * sc);
    }
    if (n < 256) wposA[n] = f2bf(w_pos[n]);    // unscaled: rel path
    for (int idx = n; idx < 14*128; idx += 512) wposA[256 + idx] = 0;
}

// ---- main decoder: 512 thr / 8 waves; wave w owns h-cols 16w..16w+15
//      (gate rows {16w+128g}); weights 64 VGPR/wave; 4 waves/SIMD ----
__global__ __launch_bounds__(512, 4) void dec_kernel(
    const float* __restrict__ lpr,             // (B,2)
    const float* __restrict__ hh,              // (B,128)
    const float* __restrict__ ch,              // (B,128)
    const float* __restrict__ b_pos,           // (2)
    const unsigned short* __restrict__ wposA,  // (16,128) bf16
    const unsigned short* __restrict__ weff,   // (512,128) bf16 pre-scaled
    const float* __restrict__ beff,            // (512) pre-scaled
    const float* __restrict__ m2,              // (2,512) pre-scaled
    float* __restrict__ out)                   // rels (32,B,2) ++ h (B,128)
{
    // h tile, XOR-swizzled at 16B-block granularity: logical col C of row l is
    // stored at physical col (( (C>>3) ^ l ) << 3) | (C&7). Reads (b128) and
    // writes (b64) both land <=2-way per bank -> free.
    __shared__ __align__(16) unsigned short lh[2][16][128];
    __shared__ float ubuf[16][2];
    __shared__ __align__(16) float hsh[16][132];   // final-h staging (+pad)
    __shared__ float biasS[512];
    __shared__ __align__(16) unsigned short wposS[16*128];

    const int tid  = threadIdx.x;
    const int w    = tid >> 6;                 // 0..7
    const int lane = tid & 63;
    const int q    = lane >> 4;
    const int l    = lane & 15;
    const int row0 = blockIdx.x << 4;
    const int batch = row0 + l;
    const int hb   = w << 4;                   // h-col base for this wave

    // stage bias + w_pos into LDS
    biasS[tid] = beff[tid];
    *(uint2*)&wposS[tid << 2] = *(const uint2*)(wposA + (tid << 2));

    // resident W_eff A-frags: gate rows {128g + hb + l}, g = i,f,g,o
    bf16_8 wA[4][4];
#pragma unroll
    for (int g = 0; g < 4; ++g){
        int gr = (g << 7) + hb + l;
#pragma unroll
        for (int kt = 0; kt < 4; ++kt)
            wA[g][kt] = *(const bf16_8*)(weff + (gr << 7) + kt*32 + (q << 3));
    }

    // c state fp32 from global: c[batch l][hb + 4q + r4]
    float4v cst = *(const float4v*)(ch + (batch << 7) + hb + (q << 2));

    // h0 B-frags from global (fp32 -> bf16)
    bf16_8 b[4];
#pragma unroll
    for (int kt = 0; kt < 4; ++kt){
        const float* ph = hh + (batch << 7) + kt*32 + (q << 3);
        float4v h0 = *(const float4v*)ph;
        float4v h1 = *(const float4v*)(ph + 4);
        bf16_8 t;
        t[0]=(__bf16)h0[0]; t[1]=(__bf16)h0[1]; t[2]=(__bf16)h0[2]; t[3]=(__bf16)h0[3];
        t[4]=(__bf16)h1[0]; t[5]=(__bf16)h1[1]; t[6]=(__bf16)h1[2]; t[7]=(__bf16)h1[3];
        b[kt] = t;
    }
    const float bp0 = b_pos[0], bp1 = b_pos[1];

    __syncthreads();                           // biasS / wposS ready

    // wave0: r_{-1} = w_pos·h0 + b_pos ; u0' = lpr - r_{-1}
    if (w == 0){
        bf16_8 wp[4];
#pragma unroll
        for (int kt = 0; kt < 4; ++kt)
            wp[kt] = *(const bf16_8*)&wposS[(l << 7) + kt*32 + (q << 3)];
        float4v r = {0.f, 0.f, 0.f, 0.f};
#pragma unroll
        for (int kt = 0; kt < 4; ++kt)
            r = __builtin_amdgcn_mfma_f32_16x16x32_bf16(wp[kt], b[kt], r, 0, 0, 0);
        if (q == 0){
            float2v lp = *(const float2v*)(lpr + (batch << 1));
            ubuf[l][0] = lp[0] - (r[0] + bp0);
            ubuf[l][1] = lp[1] - (r[1] + bp1);
        }
    }
    __syncthreads();

    float4v acc[4];

    auto do_gates = [&](){
#pragma unroll
        for (int g = 0; g < 4; ++g){           // bias loaded fresh each step
            volatile const float* bp = &biasS[(g << 7) + hb + (q << 2)];
            float4v c0 = {bp[0], bp[1], bp[2], bp[3]};
            acc[g] = __builtin_amdgcn_mfma_f32_16x16x32_bf16(wA[g][0], b[0], c0, 0, 0, 0);
        }
#pragma unroll
        for (int kt = 1; kt < 4; ++kt)
#pragma unroll
            for (int g = 0; g < 4; ++g)
                acc[g] = __builtin_amdgcn_mfma_f32_16x16x32_bf16(wA[g][kt], b[kt], acc[g], 0, 0, 0);
    };

    // merged-reciprocal LSTM cell: 5 exp2 + 2 rcp per element, 4 elem/lane
    auto do_elem_write = [&](int buf, bool finalh){
        bf16_4 hv;
#pragma unroll
        for (int r4 = 0; r4 < 4; ++r4){
            float ei = __builtin_amdgcn_exp2f(acc[0][r4]);  // e^{-i}
            float ef = __builtin_amdgcn_exp2f(acc[1][r4]);  // e^{-f}
            float eg = __builtin_amdgcn_exp2f(acc[2][r4]);  // e^{-2g}
            float pi_ = 1.f + ei, pf = 1.f + ef;
            float pg  = 1.f + eg, mg = 1.f - eg;
            float t2  = pi_ * pg;
            float den = pf * t2;
            float num = fmaf(cst[r4], t2, pf * mg);
            float c2  = num * __builtin_amdgcn_rcpf(den);
            float eo  = __builtin_amdgcn_exp2f(acc[3][r4]); // e^{-o}
            float ec  = __builtin_amdgcn_exp2f(c2 * SC2);   // e^{-2c2}
            float po = 1.f + eo, pc = 1.f + ec, mc = 1.f - ec;
            float h2 = mc * __builtin_amdgcn_rcpf(po * pc);
            cst[r4] = c2;
            hv[r4] = (__bf16)h2;
            if (finalh) hsh[l][hb + (q << 2) + r4] = h2;
        }
        int pcol = ((((w << 1) | (q >> 1)) ^ l) << 3) | ((q & 1) << 2);
        *(bf16_4*)&lh[buf][l][pcol] = hv;      // swizzled packed b64
    };

    auto reload_and_rel = [&](int buf, int t){
#pragma unroll
        for (int kt = 0; kt < 4; ++kt){
            int pcol = (((kt << 2) | q) ^ l) << 3;
            b[kt] = *(const bf16_8*)&lh[buf][l][pcol];
        }
        if (w == (t & 7)){                     // rotate rel duty across waves
            bf16_8 wp[4];
#pragma unroll
            for (int kt = 0; kt < 4; ++kt)
                wp[kt] = *(const bf16_8*)&wposS[(l << 7) + kt*32 + (q << 3)];
            float4v r = {0.f, 0.f, 0.f, 0.f};
#pragma unroll
            for (int kt = 0; kt < 4; ++kt)
                r = __builtin_amdgcn_mfma_f32_16x16x32_bf16(wp[kt], b[kt], r, 0, 0, 0);
            if (q == 0){
                float2v rv;
                rv[0] = r[0] + bp0;
                rv[1] = r[1] + bp1;
                *(float2v*)(out + t*(B_TOT*2) + (batch << 1)) = rv;
            }
        }
    };

    // ---- step 0 (peeled: rank-2 input correction along the gate dim) ----
    do_gates();
    {
        float u0 = ubuf[l][0], u1 = ubuf[l][1];
#pragma unroll
        for (int g = 0; g < 4; ++g){
            int g0 = (g << 7) + hb + (q << 2);
            float4v ma = *(const float4v*)(m2 + g0);
            float4v mb = *(const float4v*)(m2 + 512 + g0);
#pragma unroll
            for (int r4 = 0; r4 < 4; ++r4)
                acc[g][r4] += u0*ma[r4] + u1*mb[r4];
        }
    }
    do_elem_write(1, false);
    __syncthreads();
    reload_and_rel(1, 0);

    // ---- steps 1..31 ----
    for (int t = 1; t < SEQ; ++t){
        do_gates();
        do_elem_write((t + 1) & 1, t == SEQ - 1);
        __syncthreads();
        reload_and_rel((t + 1) & 1, t);
    }

    // ---- coalesced final-h store ----
    __syncthreads();
    {
        int r = tid >> 5, c4 = (tid & 31) << 2;
        float4v v = *(const float4v*)&hsh[r][c4];
        *(float4v*)(out + SEQ*B_TOT*2 + ((row0 + r) << 7) + c4) = v;
    }
}

extern "C" void kernel_launch(void* const* d_in, const int* in_sizes, int n_in,
                              void* d_out, int out_size, void* d_ws, size_t ws_size,
                              hipStream_t stream)
{
    (void)in_sizes; (void)n_in; (void)out_size; (void)ws_size;

    const float* lpr   = (const float*)d_in[1];
    const float* hh    = (const float*)d_in[2];
    const float* ch    = (const float*)d_in[3];
    const float* w_ih  = (const float*)d_in[5];
    const float* w_hh  = (const float*)d_in[6];
    const float* b_ih  = (const float*)d_in[7];
    const float* b_hh  = (const float*)d_in[8];
    const float* w_emb = (const float*)d_in[9];
    const float* b_emb = (const float*)d_in[10];
    const float* w_pos = (const float*)d_in[11];
    const float* b_pos = (const float*)d_in[12];

    unsigned short* weff  = (unsigned short*)d_ws;                     // 512*128 bf16
    float* beff           = (float*)((char*)d_ws + 131072);            // 512 f32
    float* m2             = (float*)((char*)d_ws + 131072 + 2048);     // 1024 f32
    unsigned short* wposA = (unsigned short*)((char*)d_ws + 131072 + 2048 + 4096); // 16*128 bf16

    hipLaunchKernelGGL(prep_kernel, dim3(1), dim3(512), 0, stream,
                       w_ih, w_hh, b_ih, b_hh, w_emb, b_emb, w_pos, b_pos,
                       weff, beff, m2, wposA);
    hipLaunchKernelGGL(dec_kernel, dim3(B_TOT/16), dim3(512), 0, stream,
                       lpr, hh, ch, b_pos, wposA, weff, beff, m2,
                       (float*)d_out);
}

// Round 6
// 594.878 us; speedup vs baseline: 1.6151x; 1.6151x over previous
//
#include <hip/hip_runtime.h>

#define B_TOT 65536
#define SEQ   32

typedef __bf16 bf16_8 __attribute__((ext_vector_type(8)));
typedef __bf16 bf16_4 __attribute__((ext_vector_type(4)));
typedef float  float4v __attribute__((ext_vector_type(4)));
typedef float  float2v __attribute__((ext_vector_type(2)));

#define SC1 (-1.4426950408889634f)   // -log2(e): i,f,o gate rows
#define SC2 (-2.8853900817779268f)   // -2*log2(e): g gate rows (and tanh(c2))

__device__ inline unsigned short f2bf(float f){
    unsigned u = __builtin_bit_cast(unsigned, f);
    u += 0x7FFFu + ((u >> 16) & 1u);           // round-to-nearest-even
    return (unsigned short)(u >> 16);
}

// ---- prep: W_eff = w_hh.T + w_pos.T @ (w_emb.T @ w_ih.T); biases folded;
// rows pre-scaled by -log2e (i,f,o) / -2log2e (g) so exp2 needs no mul. ----
__global__ void prep_kernel(const float* __restrict__ w_ih,
                            const float* __restrict__ w_hh,
                            const float* __restrict__ b_ih,
                            const float* __restrict__ b_hh,
                            const float* __restrict__ w_emb,
                            const float* __restrict__ b_emb,
                            const float* __restrict__ w_pos,
                            const float* __restrict__ b_pos,
                            unsigned short* __restrict__ weff,
                            float* __restrict__ beff,
                            float* __restrict__ m2,
                            unsigned short* __restrict__ wposA)
{
    int n = threadIdx.x;                       // 512 threads, one gate row each
    float m20 = 0.f, m21 = 0.f, bi = 0.f;
    for (int e = 0; e < 64; ++e){
        float wv = w_ih[n*64 + e];
        m20 += w_emb[e*2 + 0] * wv;
        m21 += w_emb[e*2 + 1] * wv;
        bi  += b_emb[e] * wv;
    }
    float sc = ((n >> 7) == 2) ? SC2 : SC1;    // gate order [i,f,g,o]
    m2[n]       = m20 * sc;
    m2[512 + n] = m21 * sc;
    beff[n] = (b_ih[n] + b_hh[n] + bi + b_pos[0]*m20 + b_pos[1]*m21) * sc;
    for (int k = 0; k < 128; ++k){
        float wv = w_hh[n*128 + k] + w_pos[k]*m20 + w_pos[128 + k]*m21;
        weff[n*128 + k] = f2bf(wv * sc);
    }
    if (n < 256) wposA[n] = f2bf(w_pos[n]);    // unscaled: rel path
    for (int idx = n; idx < 14*128; idx += 512) wposA[256 + idx] = 0;
}

// ---- main decoder: 512 thr / 8 waves; wave w owns h-cols 16w..16w+15,
//      gate rows {128g + 16w + l}; weights 64 VGPR/wave, target 4 waves/SIMD ----
__global__ __launch_bounds__(512, 4) void dec_kernel(
    const float* __restrict__ lpr,             // (B,2)
    const float* __restrict__ hh,              // (B,128)
    const float* __restrict__ ch,              // (B,128)
    const float* __restrict__ b_pos,           // (2)
    const unsigned short* __restrict__ wposA,  // (16,128) bf16
    const unsigned short* __restrict__ weff,   // (512,128) bf16 pre-scaled
    const float* __restrict__ beff,            // (512) pre-scaled
    const float* __restrict__ m2,              // (2,512) pre-scaled
    float* __restrict__ out,                   // rels (32,B,2) ++ h (B,128)
    int tmask)                                 // always 0 (defeats LICM of wp)
{
    // XOR-swizzled h tile: logical col C of row l stored at
    // pcol = (((C>>3) ^ l) << 3) | (C&7)  -> <=2-way banking for b64/b128.
    __shared__ __align__(16) unsigned short lh[2][16][128];
    __shared__ __align__(16) unsigned short wposS[16*128];
    __shared__ float ubuf[16][2];

    const int tid  = threadIdx.x;
    const int w    = tid >> 6;                 // 0..7
    const int lane = tid & 63;
    const int q    = lane >> 4;
    const int l    = lane & 15;
    const int row0 = blockIdx.x << 4;
    const int batch = row0 + l;
    const int hb   = w << 4;                   // h-col base for this wave

    // stage w_pos into LDS (4 KB) + h0 -> lh[0] (coalesced, bf16, swizzled)
    *(uint2*)&wposS[tid << 2] = *(const uint2*)(wposA + (tid << 2));
    {
        int r = tid >> 5, c = (tid & 31) << 2;          // 4 floats/thread
        float4v v = *(const float4v*)(hh + ((row0 + r) << 7) + c);
        bf16_4 hv;
        hv[0]=(__bf16)v[0]; hv[1]=(__bf16)v[1]; hv[2]=(__bf16)v[2]; hv[3]=(__bf16)v[3];
        int pcol = ((((c >> 3) ^ r) << 3)) | (c & 7);
        *(bf16_4*)&lh[0][r][pcol] = hv;
    }

    // resident W_eff A-frags (64 VGPR) + bias (16) + c-state (4)
    bf16_8 wA[4][4];
#pragma unroll
    for (int g = 0; g < 4; ++g){
        int gr = (g << 7) + hb + l;
#pragma unroll
        for (int kt = 0; kt < 4; ++kt)
            wA[g][kt] = *(const bf16_8*)(weff + (gr << 7) + kt*32 + (q << 3));
    }
    float4v bias4[4];
#pragma unroll
    for (int g = 0; g < 4; ++g)
        bias4[g] = *(const float4v*)(beff + (g << 7) + hb + (q << 2));
    float4v cst = *(const float4v*)(ch + (batch << 7) + hb + (q << 2));
    const float bp0 = b_pos[0], bp1 = b_pos[1];

    __syncthreads();                           // lh[0], wposS ready

    float4v acc[4];

    // fused gate+rel MFMA pass over h_t in lh[t&1]; duty wave also gets r
    auto fused = [&](int t, bool store_rel) -> float4v {
        const int rbuf = t & 1;
        const bool duty = (w == (t & 7));
        float4v r = {0.f, 0.f, 0.f, 0.f};
#pragma unroll
        for (int kt = 0; kt < 4; ++kt){
            int pcol = (((kt << 2) | q) ^ l) << 3;
            bf16_8 bc = *(const bf16_8*)&lh[rbuf][l][pcol];
            if (kt == 0){
#pragma unroll
                for (int g = 0; g < 4; ++g)
                    acc[g] = __builtin_amdgcn_mfma_f32_16x16x32_bf16(wA[g][0], bc, bias4[g], 0, 0, 0);
            } else {
#pragma unroll
                for (int g = 0; g < 4; ++g)
                    acc[g] = __builtin_amdgcn_mfma_f32_16x16x32_bf16(wA[g][kt], bc, acc[g], 0, 0, 0);
            }
            if (duty){   // t-dependent addr (tmask==0) defeats hoisting
                bf16_8 wpc = *(const bf16_8*)&wposS[(l << 7) + kt*32 + (q << 3) + (t & tmask)];
                r = __builtin_amdgcn_mfma_f32_16x16x32_bf16(wpc, bc, r, 0, 0, 0);
            }
        }
        if (duty && store_rel && q == 0){
            float2v rv; rv[0] = r[0] + bp0; rv[1] = r[1] + bp1;
            *(float2v*)(out + (t - 1)*(B_TOT*2) + (batch << 1)) = rv;
        }
        return r;
    };

    // merged-reciprocal LSTM cell: 5 exp2 + 2 rcp per element, 4 elem/lane
    auto elemwise = [&](int wbuf, bool finalh){
        bf16_4 hv; float4v hf;
#pragma unroll
        for (int r4 = 0; r4 < 4; ++r4){
            float ei = __builtin_amdgcn_exp2f(acc[0][r4]);  // e^{-i}
            float ef = __builtin_amdgcn_exp2f(acc[1][r4]);  // e^{-f}
            float eg = __builtin_amdgcn_exp2f(acc[2][r4]);  // e^{-2g}
            float pi_ = 1.f + ei, pf = 1.f + ef;
            float pg  = 1.f + eg, mg = 1.f - eg;
            float t2  = pi_ * pg;
            float den = pf * t2;
            float num = fmaf(cst[r4], t2, pf * mg);
            float c2  = num * __builtin_amdgcn_rcpf(den);
            float eo  = __builtin_amdgcn_exp2f(acc[3][r4]); // e^{-o}
            float ec  = __builtin_amdgcn_exp2f(c2 * SC2);   // e^{-2c2}
            float po = 1.f + eo, pc = 1.f + ec, mc = 1.f - ec;
            float h2 = mc * __builtin_amdgcn_rcpf(po * pc);
            cst[r4] = c2;
            hv[r4] = (__bf16)h2;
            hf[r4] = h2;
        }
        int pcol = ((((w << 1) | (q >> 1)) ^ l) << 3) | ((q & 1) << 2);
        *(bf16_4*)&lh[wbuf][l][pcol] = hv;
        if (finalh)
            *(float4v*)(out + SEQ*B_TOT*2 + (batch << 7) + hb + (q << 2)) = hf;
    };

    // ---- step 0 (peeled: rank-2 input correction; duty wave 0 feeds ubuf) ----
    {
        float4v r0 = fused(0, false);
        if (w == 0 && q == 0){
            float2v lp = *(const float2v*)(lpr + (batch << 1));
            ubuf[l][0] = lp[0] - (r0[0] + bp0);
            ubuf[l][1] = lp[1] - (r0[1] + bp1);
        }
        __syncthreads();
        float u0 = ubuf[l][0], u1 = ubuf[l][1];
#pragma unroll
        for (int g = 0; g < 4; ++g){
            int g0 = (g << 7) + hb + (q << 2);
            float4v ma = *(const float4v*)(m2 + g0);
            float4v mb = *(const float4v*)(m2 + 512 + g0);
#pragma unroll
            for (int r4 = 0; r4 < 4; ++r4)
                acc[g][r4] += u0*ma[r4] + u1*mb[r4];
        }
        elemwise(1, false);
        __syncthreads();
    }

    // ---- steps 1..31 ----
#pragma unroll 1
    for (int t = 1; t < SEQ; ++t){
        fused(t, true);                          // stores rel[t-1]
        elemwise((t + 1) & 1, t == SEQ - 1);     // writes h_{t+1}; t=31 -> hN
        __syncthreads();
    }

    // ---- epilogue: rel[31] = w_pos·h_32 + b_pos (h_32 in lh[0]) ----
    if (w == 0){
        float4v r = {0.f, 0.f, 0.f, 0.f};
#pragma unroll
        for (int kt = 0; kt < 4; ++kt){
            int pcol = (((kt << 2) | q) ^ l) << 3;
            bf16_8 bc = *(const bf16_8*)&lh[0][l][pcol];
            bf16_8 wpc = *(const bf16_8*)&wposS[(l << 7) + kt*32 + (q << 3)];
            r = __builtin_amdgcn_mfma_f32_16x16x32_bf16(wpc, bc, r, 0, 0, 0);
        }
        if (q == 0){
            float2v rv; rv[0] = r[0] + bp0; rv[1] = r[1] + bp1;
            *(float2v*)(out + (SEQ - 1)*(B_TOT*2) + (batch << 1)) = rv;
        }
    }
}

extern "C" void kernel_launch(void* const* d_in, const int* in_sizes, int n_in,
                              void* d_out, int out_size, void* d_ws, size_t ws_size,
                              hipStream_t stream)
{
    (void)in_sizes; (void)n_in; (void)out_size; (void)ws_size;

    const float* lpr   = (const float*)d_in[1];
    const float* hh    = (const float*)d_in[2];
    const float* ch    = (const float*)d_in[3];
    const float* w_ih  = (const float*)d_in[5];
    const float* w_hh  = (const float*)d_in[6];
    const float* b_ih  = (const float*)d_in[7];
    const float* b_hh  = (const float*)d_in[8];
    const float* w_emb = (const float*)d_in[9];
    const float* b_emb = (const float*)d_in[10];
    const float* w_pos = (const float*)d_in[11];
    const float* b_pos = (const float*)d_in[12];

    unsigned short* weff  = (unsigned short*)d_ws;                     // 512*128 bf16
    float* beff           = (float*)((char*)d_ws + 131072);            // 512 f32
    float* m2             = (float*)((char*)d_ws + 131072 + 2048);     // 1024 f32
    unsigned short* wposA = (unsigned short*)((char*)d_ws + 131072 + 2048 + 4096); // 16*128 bf16

    hipLaunchKernelGGL(prep_kernel, dim3(1), dim3(512), 0, stream,
                       w_ih, w_hh, b_ih, b_hh, w_emb, b_emb, w_pos, b_pos,
                       weff, beff, m2, wposA);
    hipLaunchKernelGGL(dec_kernel, dim3(B_TOT/16), dim3(512), 0, stream,
                       lpr, hh, ch, b_pos, wposA, weff, beff, m2,
                       (float*)d_out, 0);
}

// Round 7
// 534.068 us; speedup vs baseline: 1.7990x; 1.1139x over previous
//
#include <hip/hip_runtime.h>

#define B_TOT 65536
#define SEQ   32

typedef __bf16 bf16_8 __attribute__((ext_vector_type(8)));
typedef __bf16 bf16_4 __attribute__((ext_vector_type(4)));
typedef float  float4v __attribute__((ext_vector_type(4)));
typedef float  float2v __attribute__((ext_vector_type(2)));

#define SC1 (-1.4426950408889634f)   // -log2(e): i,f,o gate rows
#define SC2 (-2.8853900817779268f)   // -2*log2(e): g gate rows (and tanh(c2))

__device__ inline unsigned short f2bf(float f){
    unsigned u = __builtin_bit_cast(unsigned, f);
    u += 0x7FFFu + ((u >> 16) & 1u);           // round-to-nearest-even
    return (unsigned short)(u >> 16);
}

// ---- prep: W_eff = w_hh.T + w_pos.T @ (w_emb.T @ w_ih.T); biases folded;
// rows pre-scaled by -log2e (i,f,o) / -2log2e (g) so exp2 needs no mul. ----
__global__ void prep_kernel(const float* __restrict__ w_ih,
                            const float* __restrict__ w_hh,
                            const float* __restrict__ b_ih,
                            const float* __restrict__ b_hh,
                            const float* __restrict__ w_emb,
                            const float* __restrict__ b_emb,
                            const float* __restrict__ w_pos,
                            const float* __restrict__ b_pos,
                            unsigned short* __restrict__ weff,
                            float* __restrict__ beff,
                            float* __restrict__ m2,
                            unsigned short* __restrict__ wposA)
{
    int n = threadIdx.x;                       // 512 threads, one gate row each
    float m20 = 0.f, m21 = 0.f, bi = 0.f;
    for (int e = 0; e < 64; ++e){
        float wv = w_ih[n*64 + e];
        m20 += w_emb[e*2 + 0] * wv;
        m21 += w_emb[e*2 + 1] * wv;
        bi  += b_emb[e] * wv;
    }
    float sc = ((n >> 7) == 2) ? SC2 : SC1;    // gate order [i,f,g,o]
    m2[n]       = m20 * sc;
    m2[512 + n] = m21 * sc;
    beff[n] = (b_ih[n] + b_hh[n] + bi + b_pos[0]*m20 + b_pos[1]*m21) * sc;
    for (int k = 0; k < 128; ++k){
        float wv = w_hh[n*128 + k] + w_pos[k]*m20 + w_pos[128 + k]*m21;
        weff[n*128 + k] = f2bf(wv * sc);
    }
    if (n < 256) wposA[n] = f2bf(w_pos[n]);    // unscaled: rel path
    for (int idx = n; idx < 14*128; idx += 512) wposA[256 + idx] = 0;
}

// ---- main decoder: 512 thr / 8 waves; 32 batch rows as two groups (A,B);
//      wave owns h-cols 16w..16w+15 for both groups; dual-stream per wave ----
__global__ __launch_bounds__(512, 2) void dec_kernel(
    const float* __restrict__ lpr,             // (B,2)
    const float* __restrict__ hh,              // (B,128)
    const float* __restrict__ ch,              // (B,128)
    const float* __restrict__ b_pos,           // (2)
    const unsigned short* __restrict__ wposA,  // (16,128) bf16
    const unsigned short* __restrict__ weff,   // (512,128) bf16 pre-scaled
    const float* __restrict__ beff,            // (512) pre-scaled
    const float* __restrict__ m2,              // (2,512) pre-scaled
    float* __restrict__ out)                   // rels (32,B,2) ++ h (B,128)
{
    // XOR-swizzled h tiles (2 groups x 2 buffers): logical col C of row l at
    // pcol = (((C>>3) ^ l) << 3) | (C&7).
    __shared__ __align__(16) unsigned short lh[2][2][16][128];
    __shared__ __align__(16) unsigned short wposS[16][136];  // padded rows
    __shared__ float ubuf[32][2];

    const int tid  = threadIdx.x;
    const int w    = tid >> 6;                 // 0..7
    const int lane = tid & 63;
    const int q    = lane >> 4;
    const int l    = lane & 15;
    const int row0 = blockIdx.x << 5;          // 32 rows/block
    const int batchA = row0 + l;
    const int batchB = row0 + 16 + l;
    const int hb   = w << 4;                   // h-col base for this wave

    // stage w_pos into padded LDS (512 thr x 4 elems)
    {
        int idx = tid << 2;
        *(uint2*)&wposS[idx >> 7][idx & 127] = *(const uint2*)(wposA + idx);
    }
    // stage h0 for both groups (512 thr x 8 floats), bf16 + swizzle
    {
        int r = tid >> 4, c = (tid & 15) << 3;
        const float* ph = hh + ((row0 + r) << 7) + c;
        float4v v0 = *(const float4v*)ph;
        float4v v1 = *(const float4v*)(ph + 4);
        bf16_8 hv;
        hv[0]=(__bf16)v0[0]; hv[1]=(__bf16)v0[1]; hv[2]=(__bf16)v0[2]; hv[3]=(__bf16)v0[3];
        hv[4]=(__bf16)v1[0]; hv[5]=(__bf16)v1[1]; hv[6]=(__bf16)v1[2]; hv[7]=(__bf16)v1[3];
        int rl = r & 15;
        int pcol = ((c >> 3) ^ rl) << 3;
        *(bf16_8*)&lh[r >> 4][0][rl][pcol] = hv;
    }

    // resident W_eff A-frags (64 VGPR) + bias (16) + wp (16), shared by groups
    bf16_8 wA[4][4];
#pragma unroll
    for (int g = 0; g < 4; ++g){
        int gr = (g << 7) + hb + l;
#pragma unroll
        for (int kt = 0; kt < 4; ++kt)
            wA[g][kt] = *(const bf16_8*)(weff + (gr << 7) + kt*32 + (q << 3));
    }
    float4v bias4[4];
#pragma unroll
    for (int g = 0; g < 4; ++g)
        bias4[g] = *(const float4v*)(beff + (g << 7) + hb + (q << 2));
    const float bp0 = b_pos[0], bp1 = b_pos[1];

    // c states, fp32 from global
    float4v cstA = *(const float4v*)(ch + (batchA << 7) + hb + (q << 2));
    float4v cstB = *(const float4v*)(ch + (batchB << 7) + hb + (q << 2));

    __syncthreads();                           // lh[*][0], wposS ready

    // w_pos frags from LDS once (padded rows -> ~2-way banking)
    bf16_8 wp[4];
#pragma unroll
    for (int kt = 0; kt < 4; ++kt)
        wp[kt] = *(const bf16_8*)&wposS[l][kt*32 + (q << 3)];

    float4v accA[4], accB[4];

    auto fused = [&](float4v (&acc)[4], const unsigned short (*tile)[128],
                     bool duty) -> float4v {
        float4v r = {0.f, 0.f, 0.f, 0.f};
#pragma unroll
        for (int kt = 0; kt < 4; ++kt){
            int pcol = (((kt << 2) | q) ^ l) << 3;
            bf16_8 bc = *(const bf16_8*)&tile[l][pcol];
            if (kt == 0){
#pragma unroll
                for (int g = 0; g < 4; ++g)
                    acc[g] = __builtin_amdgcn_mfma_f32_16x16x32_bf16(wA[g][0], bc, bias4[g], 0, 0, 0);
            } else {
#pragma unroll
                for (int g = 0; g < 4; ++g)
                    acc[g] = __builtin_amdgcn_mfma_f32_16x16x32_bf16(wA[g][kt], bc, acc[g], 0, 0, 0);
            }
            if (duty)
                r = __builtin_amdgcn_mfma_f32_16x16x32_bf16(wp[kt], bc, r, 0, 0, 0);
        }
        return r;
    };

    // merged-reciprocal LSTM cell: 5 exp2 + 2 rcp per element, 4 elem/lane
    auto elemwise = [&](float4v (&acc)[4], float4v& cst,
                        unsigned short (*tile)[128], bool finalh, int batch){
        bf16_4 hv; float4v hf;
#pragma unroll
        for (int r4 = 0; r4 < 4; ++r4){
            float ei = __builtin_amdgcn_exp2f(acc[0][r4]);  // e^{-i}
            float ef = __builtin_amdgcn_exp2f(acc[1][r4]);  // e^{-f}
            float eg = __builtin_amdgcn_exp2f(acc[2][r4]);  // e^{-2g}
            float pi_ = 1.f + ei, pf = 1.f + ef;
            float pg  = 1.f + eg, mg = 1.f - eg;
            float t2  = pi_ * pg;
            float den = pf * t2;
            float num = fmaf(cst[r4], t2, pf * mg);
            float c2  = num * __builtin_amdgcn_rcpf(den);
            float eo  = __builtin_amdgcn_exp2f(acc[3][r4]); // e^{-o}
            float ec  = __builtin_amdgcn_exp2f(c2 * SC2);   // e^{-2c2}
            float po = 1.f + eo, pc = 1.f + ec, mc = 1.f - ec;
            float h2 = mc * __builtin_amdgcn_rcpf(po * pc);
            cst[r4] = c2;
            hv[r4] = (__bf16)h2;
            hf[r4] = h2;
        }
        int pcol = ((((w << 1) | (q >> 1)) ^ l) << 3) | ((q & 1) << 2);
        *(bf16_4*)&tile[l][pcol] = hv;
        if (finalh)
            *(float4v*)(out + SEQ*B_TOT*2 + (batch << 7) + hb + (q << 2)) = hf;
    };

    // ---- step 0 (peeled: rank-2 input correction; wave 0 computes r_{-1}) ----
    {
        float4v rA = fused(accA, lh[0][0], w == 0);
        float4v rB = fused(accB, lh[1][0], w == 0);
        if (w == 0 && q == 0){
            float2v lpA = *(const float2v*)(lpr + (batchA << 1));
            float2v lpB = *(const float2v*)(lpr + (batchB << 1));
            ubuf[l][0]      = lpA[0] - (rA[0] + bp0);
            ubuf[l][1]      = lpA[1] - (rA[1] + bp1);
            ubuf[16 + l][0] = lpB[0] - (rB[0] + bp0);
            ubuf[16 + l][1] = lpB[1] - (rB[1] + bp1);
        }
        __syncthreads();
        float uA0 = ubuf[l][0], uA1 = ubuf[l][1];
        float uB0 = ubuf[16 + l][0], uB1 = ubuf[16 + l][1];
#pragma unroll
        for (int g = 0; g < 4; ++g){
            int g0 = (g << 7) + hb + (q << 2);
            float4v ma = *(const float4v*)(m2 + g0);
            float4v mb = *(const float4v*)(m2 + 512 + g0);
#pragma unroll
            for (int r4 = 0; r4 < 4; ++r4){
                accA[g][r4] += uA0*ma[r4] + uA1*mb[r4];
                accB[g][r4] += uB0*ma[r4] + uB1*mb[r4];
            }
        }
        elemwise(accA, cstA, lh[0][1], false, batchA);
        elemwise(accB, cstB, lh[1][1], false, batchB);
        __syncthreads();
    }

    // ---- steps 1..31 ----
#pragma unroll 1
    for (int t = 1; t < SEQ; ++t){
        const bool duty = (w == (t & 7));
        float4v rA = fused(accA, lh[0][t & 1], duty);
        float4v rB = fused(accB, lh[1][t & 1], duty);
        if (duty && q == 0){
            float2v rvA; rvA[0] = rA[0] + bp0; rvA[1] = rA[1] + bp1;
            float2v rvB; rvB[0] = rB[0] + bp0; rvB[1] = rB[1] + bp1;
            *(float2v*)(out + (t - 1)*(B_TOT*2) + (batchA << 1)) = rvA;
            *(float2v*)(out + (t - 1)*(B_TOT*2) + (batchB << 1)) = rvB;
        }
        elemwise(accA, cstA, lh[0][(t + 1) & 1], t == SEQ - 1, batchA);
        elemwise(accB, cstB, lh[1][(t + 1) & 1], t == SEQ - 1, batchB);
        __syncthreads();
    }

    // ---- epilogue: rel[31] = w_pos·h_32 + b_pos (h_32 in lh[grp][0]) ----
    if (w < 2){
        const unsigned short (*tile)[128] = lh[w][0];
        float4v r = {0.f, 0.f, 0.f, 0.f};
#pragma unroll
        for (int kt = 0; kt < 4; ++kt){
            int pcol = (((kt << 2) | q) ^ l) << 3;
            bf16_8 bc = *(const bf16_8*)&tile[l][pcol];
            r = __builtin_amdgcn_mfma_f32_16x16x32_bf16(wp[kt], bc, r, 0, 0, 0);
        }
        if (q == 0){
            float2v rv; rv[0] = r[0] + bp0; rv[1] = r[1] + bp1;
            *(float2v*)(out + (SEQ - 1)*(B_TOT*2) + ((row0 + (w << 4) + l) << 1)) = rv;
        }
    }
}

extern "C" void kernel_launch(void* const* d_in, const int* in_sizes, int n_in,
                              void* d_out, int out_size, void* d_ws, size_t ws_size,
                              hipStream_t stream)
{
    (void)in_sizes; (void)n_in; (void)out_size; (void)ws_size;

    const float* lpr   = (const float*)d_in[1];
    const float* hh    = (const float*)d_in[2];
    const float* ch    = (const float*)d_in[3];
    const float* w_ih  = (const float*)d_in[5];
    const float* w_hh  = (const float*)d_in[6];
    const float* b_ih  = (const float*)d_in[7];
    const float* b_hh  = (const float*)d_in[8];
    const float* w_emb = (const float*)d_in[9];
    const float* b_emb = (const float*)d_in[10];
    const float* w_pos = (const float*)d_in[11];
    const float* b_pos = (const float*)d_in[12];

    unsigned short* weff  = (unsigned short*)d_ws;                     // 512*128 bf16
    float* beff           = (float*)((char*)d_ws + 131072);            // 512 f32
    float* m2             = (float*)((char*)d_ws + 131072 + 2048);     // 1024 f32
    unsigned short* wposA = (unsigned short*)((char*)d_ws + 131072 + 2048 + 4096); // 16*128 bf16

    hipLaunchKernelGGL(prep_kernel, dim3(1), dim3(512), 0, stream,
                       w_ih, w_hh, b_ih, b_hh, w_emb, b_emb, w_pos, b_pos,
                       weff, beff, m2, wposA);
    hipLaunchKernelGGL(dec_kernel, dim3(B_TOT/32), dim3(512), 0, stream,
                       lpr, hh, ch, b_pos, wposA, weff, beff, m2,
                       (float*)d_out);
}